// Round 17
// baseline (305.110 us; speedup 1.0000x reference)
//
#include <hip/hip_runtime.h>

#define TT    512
#define HH    64
#define NB    4
#define NBLK  256
#define HP    80    // h batch pitch in f16 (r21: 2-way banks, free)

#define LOG2E 1.44269504f

typedef _Float16 f16x8 __attribute__((ext_vector_type(8)));
typedef float    f32x4 __attribute__((ext_vector_type(4)));

#if __has_builtin(__builtin_amdgcn_exp2f)
#define EXP2(x) __builtin_amdgcn_exp2f(x)
#else
#define EXP2(x) exp2f(x)
#endif

// r26 = r25 + ONE change: static wave priority. Each SIMD hosts one A-wave
// and one C-wave, phase-locked by the tick barrier; both start their chains
// at barrier release and contend for the same VALU/trans/LDS issue slots.
// C's chain (ds_read -> 4-chain MFMA -> pointwise -> write) is the tick
// pace-setter (r25: shortening A was neutral); A finishes early and idles
// at the barrier — but in fair round-robin it steals issue slots FROM C's
// critical path first. s_setprio(1) on the C group makes C win every
// arbitration conflict; A's ~300cy of issue fits easily in C's latency
// gaps. Role-diverse waves = the setprio-positive regime (m191 attn +4-7%;
// m190's null was same-role lockstep). Zero arithmetic change.
// r25 recap (= r21 backbone, 270us): swapped-operand MFMA (lane (n,quad)
// holds cell (unit 16w+n, batch quad) in acc[g][0], no transpose, conflicts
// ~0), rcp pointwise (r17), exp2/sign folding (r18/r19), A's x-transform as
// scalar C[0]-init hoisted pre-barrier (r25).
// LESSONS: r8 cross-block 4x. r10 16-lane pointwise 2x. r12/r15/r20/r24
// co-residency closed. r13/r22 fat waves closed. r14/r23 chain cuts
// neutral-to-negative. r16 spin-barriers worse. r17 rcp -19%. r21 -28%.
__device__ __forceinline__ float sig2_(float xs) {   // xs = -x*log2e (pre-folded)
    return __builtin_amdgcn_rcpf(1.0f + EXP2(xs));
}
__device__ __forceinline__ float tanh2_(float xs) {  // xs = 2x*log2e (pre-folded)
    return 1.0f - 2.0f * __builtin_amdgcn_rcpf(1.0f + EXP2(xs));
}

__global__ __launch_bounds__(512) void lstm_mfma(
    const float* __restrict__ x,
    const float* __restrict__ w_ih0, const float* __restrict__ w_hh0,
    const float* __restrict__ b_ih0, const float* __restrict__ b_hh0,
    const float* __restrict__ w_ih1, const float* __restrict__ w_hh1,
    const float* __restrict__ b_ih1, const float* __restrict__ b_hh1,
    const float* __restrict__ w_out, const float* __restrict__ b_out,
    float* __restrict__ out)
{
    __shared__ __align__(16) _Float16 h1T[2][4 * HP];   // h1 [batch][unit] f16
    __shared__ __align__(16) _Float16 h2T[2][4 * HP];   // h2 [batch][unit] f16
    __shared__ float xs[TT * 12];                       // x [t][d][4] fp32
    __shared__ __align__(16) float h2f[4 * 68];         // final h2 fp32
    __shared__ float lg[NB][4];

    const int tid   = threadIdx.x;
    const int group = tid >> 8;          // 0 = A (layer 1), 1 = C (layer 2)
    const int w     = (tid >> 6) & 3;    // wave-in-group
    const int lane  = tid & 63;
    const int quad  = lane >> 4;
    const int n     = lane & 15;         // B-col = weight-row-in-tile; A-row idx
    const int bq    = n >> 2;            // batch carried by this lane's A-row
    const int b0    = blockIdx.x * NB;

    // ---- persistent weight fragments (B = W^T; gate-scaled r18 folding) ----
    f16x8 whh[4][2], wih[4][2];
    f32x4 biasf[4];
    float wx[4][3];                      // A only: scaled W_ih0 row of this lane
    #pragma unroll
    for (int g_ = 0; g_ < 4; ++g_) {
        const float sc = (g_ == 2) ? (2.0f * LOG2E) : (-LOG2E);
        const int arow = 16 * w + 64 * g_ + n;        // weight row of B-col n
        const float* ph = (group == 0) ? (w_hh0 + arow * HH) : (w_hh1 + arow * HH);
        const float* pi = w_ih1 + arow * HH;
        #pragma unroll
        for (int k0 = 0; k0 < 2; ++k0) {
            #pragma unroll
            for (int j = 0; j < 8; ++j) {
                whh[g_][k0][j] = (_Float16)(sc * ph[quad * 8 + 32 * k0 + j]);
                wih[g_][k0][j] = (group == 1) ? (_Float16)(sc * pi[quad * 8 + 32 * k0 + j])
                                              : (_Float16)0.f;
            }
        }
        const float bv = sc * ((group == 0) ? (b_ih0[arow] + b_hh0[arow])
                                            : (b_ih1[arow] + b_hh1[arow]));
        #pragma unroll
        for (int r = 0; r < 4; ++r) biasf[g_][r] = bv;
        #pragma unroll
        for (int d = 0; d < 3; ++d)
            wx[g_][d] = (group == 0) ? (sc * w_ih0[arow * 3 + d]) : 0.f;
    }

    // ---- LDS init ----
    for (int i = tid; i < 2 * 4 * HP / 2; i += 512) {   // ints
        ((int*)h1T)[i] = 0;
        ((int*)h2T)[i] = 0;
    }
    for (int i = tid; i < TT * 12; i += 512) {
        const int t = i / 12, rem = i - t * 12;
        const int d = rem >> 2, b = rem & 3;
        xs[i] = x[(size_t)(b0 + b) * (TT * 3) + t * 3 + d];
    }
    __syncthreads();

    // C group = critical path: win every intra-SIMD issue arbitration.
    if (group == 1) __builtin_amdgcn_s_setprio(1);

    float creg = 0.f;    // cell c of (unit 16w+n, batch quad)

    // A: pre-compute C[0]-init for t=0 (bias + W_ih0 x(0)), ascending-k fmaf
    float ainit[4];
    if (group == 0) {
        const float* xp = xs + quad;                  // t = 0
        const float x0 = xp[0], x1 = xp[4], x2 = xp[8];
        #pragma unroll
        for (int g_ = 0; g_ < 4; ++g_)
            ainit[g_] = fmaf(wx[g_][2], x2,
                        fmaf(wx[g_][1], x1,
                        fmaf(wx[g_][0], x0, biasf[g_][0])));
    }

    for (int t = 0; t <= TT; ++t) {
        if (group == 0) {
            if (t < TT) {
                const _Float16* hsrc = h1T[(t + 1) & 1];
                const f16x8 bh0 = *(const f16x8*)(hsrc + bq * HP + quad * 8);
                const f16x8 bh1 = *(const f16x8*)(hsrc + bq * HP + quad * 8 + 32);
                f32x4 acc[4];
                #pragma unroll
                for (int g_ = 0; g_ < 4; ++g_) {
                    const f32x4 ci = {ainit[g_], ainit[g_], ainit[g_], ainit[g_]};
                    f32x4 a = __builtin_amdgcn_mfma_f32_16x16x32_f16(bh0, whh[g_][0], ci, 0, 0, 0);
                    a = __builtin_amdgcn_mfma_f32_16x16x32_f16(bh1, whh[g_][1], a, 0, 0, 0);
                    acc[g_] = a;
                }
                const float is = sig2_(acc[0][0]);
                const float fs = sig2_(acc[1][0]);
                const float gt = tanh2_(acc[2][0]);
                const float os = sig2_(acc[3][0]);
                creg = fs * creg + is * gt;
                h1T[t & 1][quad * HP + 16 * w + n] =
                    (_Float16)(os * tanh2_(creg * (2.0f * LOG2E)));
                // ---- pre-barrier tail: init for tick t+1 (xs is read-only) ----
                if (t + 1 < TT) {
                    const float* xp = xs + (t + 1) * 12 + quad;
                    const float x0 = xp[0], x1 = xp[4], x2 = xp[8];
                    #pragma unroll
                    for (int g_ = 0; g_ < 4; ++g_)
                        ainit[g_] = fmaf(wx[g_][2], x2,
                                    fmaf(wx[g_][1], x1,
                                    fmaf(wx[g_][0], x0, biasf[g_][0])));
                }
            }
        } else {
            if (t >= 1) {
                // fused K=128 matvec over [h1(t-1); h2(t-2)], 4-deep chain
                const _Float16* h1src = h1T[(t + 1) & 1];
                const _Float16* h2src = h2T[(t + 1) & 1];
                const f16x8 b10 = *(const f16x8*)(h1src + bq * HP + quad * 8);
                const f16x8 b11 = *(const f16x8*)(h1src + bq * HP + quad * 8 + 32);
                const f16x8 b20 = *(const f16x8*)(h2src + bq * HP + quad * 8);
                const f16x8 b21 = *(const f16x8*)(h2src + bq * HP + quad * 8 + 32);
                f32x4 acc[4];
                #pragma unroll
                for (int g_ = 0; g_ < 4; ++g_) {
                    f32x4 a = __builtin_amdgcn_mfma_f32_16x16x32_f16(b10, wih[g_][0], biasf[g_], 0, 0, 0);
                    a = __builtin_amdgcn_mfma_f32_16x16x32_f16(b11, wih[g_][1], a, 0, 0, 0);
                    a = __builtin_amdgcn_mfma_f32_16x16x32_f16(b20, whh[g_][0], a, 0, 0, 0);
                    a = __builtin_amdgcn_mfma_f32_16x16x32_f16(b21, whh[g_][1], a, 0, 0, 0);
                    acc[g_] = a;
                }
                const float is = sig2_(acc[0][0]);
                const float fs = sig2_(acc[1][0]);
                const float gt = tanh2_(acc[2][0]);
                const float os = sig2_(acc[3][0]);
                creg = fs * creg + is * gt;
                const float h = os * tanh2_(creg * (2.0f * LOG2E));
                h2T[t & 1][quad * HP + 16 * w + n] = (_Float16)h;   // h2(t-1)
                if (t == TT) h2f[quad * 68 + 16 * w + n] = h;       // h2(TT-1) fp32
            }
        }
        __syncthreads();
    }

    if (group == 1) __builtin_amdgcn_s_setprio(0);

    // ---- epilogue: logits + softmax on fp32 h2 ----
    if (tid < 16) {
        const int b = tid & 3, o = tid >> 2;
        float acc = b_out[o];
        #pragma unroll
        for (int j = 0; j < HH; ++j)
            acc = fmaf(w_out[o * HH + j], h2f[b * 68 + j], acc);
        lg[b][o] = acc;
    }
    __syncthreads();
    if (tid < NB) {
        const int b = tid;
        const float l0 = lg[b][0], l1 = lg[b][1], l2 = lg[b][2], l3 = lg[b][3];
        const float m  = fmaxf(fmaxf(l0, l1), fmaxf(l2, l3));
        const float e0 = __expf(l0 - m), e1 = __expf(l1 - m);
        const float e2 = __expf(l2 - m), e3 = __expf(l3 - m);
        const float sum = 1.0f / (e0 + e1 + e2 + e3);
        out[(b0 + b) * 4 + 0] = e0 * sum;
        out[(b0 + b) * 4 + 1] = e1 * sum;
        out[(b0 + b) * 4 + 2] = e2 * sum;
        out[(b0 + b) * 4 + 3] = e3 * sum;
    }
}

extern "C" void kernel_launch(void* const* d_in, const int* in_sizes, int n_in,
                              void* d_out, int out_size, void* d_ws, size_t ws_size,
                              hipStream_t stream) {
    const float* x     = (const float*)d_in[0];
    const float* w_ih0 = (const float*)d_in[1];
    const float* w_hh0 = (const float*)d_in[2];
    const float* b_ih0 = (const float*)d_in[3];
    const float* b_hh0 = (const float*)d_in[4];
    const float* w_ih1 = (const float*)d_in[5];
    const float* w_hh1 = (const float*)d_in[6];
    const float* b_ih1 = (const float*)d_in[7];
    const float* b_hh1 = (const float*)d_in[8];
    const float* w_out = (const float*)d_in[9];
    const float* b_out = (const float*)d_in[10];
    float* out = (float*)d_out;

    hipLaunchKernelGGL(lstm_mfma, dim3(NBLK), dim3(512), 0, stream,
                       x, w_ih0, w_hh0, b_ih0, b_hh0,
                       w_ih1, w_hh1, b_ih1, b_hh1,
                       w_out, b_out, out);
}

// Round 18
// 302.286 us; speedup vs baseline: 1.0093x; 1.0093x over previous
//
#include <hip/hip_runtime.h>

#define TT    512
#define HH    64
#define NB    4
#define NBLK  256
#define HP    80    // h batch pitch in f16 (r21: 2-way banks, free)

#define LOG2E 1.44269504f

typedef _Float16 f16x8 __attribute__((ext_vector_type(8)));
typedef float    f32x4 __attribute__((ext_vector_type(4)));

#if __has_builtin(__builtin_amdgcn_exp2f)
#define EXP2(x) __builtin_amdgcn_exp2f(x)
#else
#define EXP2(x) exp2f(x)
#endif

// r27 = r25 exactly (r26's setprio reverted: it measured +1% slower).
// This is the session's best kernel (~270us top-5, vs 460us at session
// start) and the terminal configuration of the mapped design space:
//   - swapped-operand MFMA (r21, -28%): A = h^T batch-replicated rows,
//     B = W^T; lane (n,quad) holds all 4 gates of cell (unit 16w+n,
//     batch quad) in acc[g][0] -> pointwise on all 64 lanes, zero
//     post-MFMA data movement, LDS bank conflicts ~0.
//   - rcp pointwise (r17, -19%): v_rcp_f32 instead of IEEE divide.
//   - exp2/sign folding (r18/r19): gate rows pre-scaled (i,f,o x-log2e,
//     g x2log2e) -> sigmoid = rcp(1+exp2(g)), tanh = 1-2*rcp(1+exp2(g)).
//   - A's x-transform as scalar C[0]-init hoisted pre-barrier (r25).
// Axes probed to null/negative: MFMA chain depth (r14/r23/r25), software
// barriers (r16), co-residency (r12/r15/r20/r24 — wall = 513 x tick,
// parallelism can't shorten the chain), wave fatness (r13/r22), setprio
// (r26). Counters show latency floor, not a pipe roofline: HBM 0.19%,
// MfmaUtil 33, VALUBusy 43. Tick ~1260cy = barrier + LDS h-hop + matvec
// + pointwise, each segment individually shortening-resistant.
__device__ __forceinline__ float sig2_(float xs) {   // xs = -x*log2e (pre-folded)
    return __builtin_amdgcn_rcpf(1.0f + EXP2(xs));
}
__device__ __forceinline__ float tanh2_(float xs) {  // xs = 2x*log2e (pre-folded)
    return 1.0f - 2.0f * __builtin_amdgcn_rcpf(1.0f + EXP2(xs));
}

__global__ __launch_bounds__(512) void lstm_mfma(
    const float* __restrict__ x,
    const float* __restrict__ w_ih0, const float* __restrict__ w_hh0,
    const float* __restrict__ b_ih0, const float* __restrict__ b_hh0,
    const float* __restrict__ w_ih1, const float* __restrict__ w_hh1,
    const float* __restrict__ b_ih1, const float* __restrict__ b_hh1,
    const float* __restrict__ w_out, const float* __restrict__ b_out,
    float* __restrict__ out)
{
    __shared__ __align__(16) _Float16 h1T[2][4 * HP];   // h1 [batch][unit] f16
    __shared__ __align__(16) _Float16 h2T[2][4 * HP];   // h2 [batch][unit] f16
    __shared__ float xs[TT * 12];                       // x [t][d][4] fp32
    __shared__ __align__(16) float h2f[4 * 68];         // final h2 fp32
    __shared__ float lg[NB][4];

    const int tid   = threadIdx.x;
    const int group = tid >> 8;          // 0 = A (layer 1), 1 = C (layer 2)
    const int w     = (tid >> 6) & 3;    // wave-in-group
    const int lane  = tid & 63;
    const int quad  = lane >> 4;
    const int n     = lane & 15;         // B-col = weight-row-in-tile; A-row idx
    const int bq    = n >> 2;            // batch carried by this lane's A-row
    const int b0    = blockIdx.x * NB;

    // ---- persistent weight fragments (B = W^T; gate-scaled r18 folding) ----
    f16x8 whh[4][2], wih[4][2];
    f32x4 biasf[4];
    float wx[4][3];                      // A only: scaled W_ih0 row of this lane
    #pragma unroll
    for (int g_ = 0; g_ < 4; ++g_) {
        const float sc = (g_ == 2) ? (2.0f * LOG2E) : (-LOG2E);
        const int arow = 16 * w + 64 * g_ + n;        // weight row of B-col n
        const float* ph = (group == 0) ? (w_hh0 + arow * HH) : (w_hh1 + arow * HH);
        const float* pi = w_ih1 + arow * HH;
        #pragma unroll
        for (int k0 = 0; k0 < 2; ++k0) {
            #pragma unroll
            for (int j = 0; j < 8; ++j) {
                whh[g_][k0][j] = (_Float16)(sc * ph[quad * 8 + 32 * k0 + j]);
                wih[g_][k0][j] = (group == 1) ? (_Float16)(sc * pi[quad * 8 + 32 * k0 + j])
                                              : (_Float16)0.f;
            }
        }
        const float bv = sc * ((group == 0) ? (b_ih0[arow] + b_hh0[arow])
                                            : (b_ih1[arow] + b_hh1[arow]));
        #pragma unroll
        for (int r = 0; r < 4; ++r) biasf[g_][r] = bv;
        #pragma unroll
        for (int d = 0; d < 3; ++d)
            wx[g_][d] = (group == 0) ? (sc * w_ih0[arow * 3 + d]) : 0.f;
    }

    // ---- LDS init ----
    for (int i = tid; i < 2 * 4 * HP / 2; i += 512) {   // ints
        ((int*)h1T)[i] = 0;
        ((int*)h2T)[i] = 0;
    }
    for (int i = tid; i < TT * 12; i += 512) {
        const int t = i / 12, rem = i - t * 12;
        const int d = rem >> 2, b = rem & 3;
        xs[i] = x[(size_t)(b0 + b) * (TT * 3) + t * 3 + d];
    }
    __syncthreads();

    float creg = 0.f;    // cell c of (unit 16w+n, batch quad)

    // A: pre-compute C[0]-init for t=0 (bias + W_ih0 x(0)), ascending-k fmaf
    float ainit[4];
    if (group == 0) {
        const float* xp = xs + quad;                  // t = 0
        const float x0 = xp[0], x1 = xp[4], x2 = xp[8];
        #pragma unroll
        for (int g_ = 0; g_ < 4; ++g_)
            ainit[g_] = fmaf(wx[g_][2], x2,
                        fmaf(wx[g_][1], x1,
                        fmaf(wx[g_][0], x0, biasf[g_][0])));
    }

    for (int t = 0; t <= TT; ++t) {
        if (group == 0) {
            if (t < TT) {
                const _Float16* hsrc = h1T[(t + 1) & 1];
                const f16x8 bh0 = *(const f16x8*)(hsrc + bq * HP + quad * 8);
                const f16x8 bh1 = *(const f16x8*)(hsrc + bq * HP + quad * 8 + 32);
                f32x4 acc[4];
                #pragma unroll
                for (int g_ = 0; g_ < 4; ++g_) {
                    const f32x4 ci = {ainit[g_], ainit[g_], ainit[g_], ainit[g_]};
                    f32x4 a = __builtin_amdgcn_mfma_f32_16x16x32_f16(bh0, whh[g_][0], ci, 0, 0, 0);
                    a = __builtin_amdgcn_mfma_f32_16x16x32_f16(bh1, whh[g_][1], a, 0, 0, 0);
                    acc[g_] = a;
                }
                const float is = sig2_(acc[0][0]);
                const float fs = sig2_(acc[1][0]);
                const float gt = tanh2_(acc[2][0]);
                const float os = sig2_(acc[3][0]);
                creg = fs * creg + is * gt;
                h1T[t & 1][quad * HP + 16 * w + n] =
                    (_Float16)(os * tanh2_(creg * (2.0f * LOG2E)));
                // ---- pre-barrier tail: init for tick t+1 (xs is read-only) ----
                if (t + 1 < TT) {
                    const float* xp = xs + (t + 1) * 12 + quad;
                    const float x0 = xp[0], x1 = xp[4], x2 = xp[8];
                    #pragma unroll
                    for (int g_ = 0; g_ < 4; ++g_)
                        ainit[g_] = fmaf(wx[g_][2], x2,
                                    fmaf(wx[g_][1], x1,
                                    fmaf(wx[g_][0], x0, biasf[g_][0])));
                }
            }
        } else {
            if (t >= 1) {
                // fused K=128 matvec over [h1(t-1); h2(t-2)], 4-deep chain
                const _Float16* h1src = h1T[(t + 1) & 1];
                const _Float16* h2src = h2T[(t + 1) & 1];
                const f16x8 b10 = *(const f16x8*)(h1src + bq * HP + quad * 8);
                const f16x8 b11 = *(const f16x8*)(h1src + bq * HP + quad * 8 + 32);
                const f16x8 b20 = *(const f16x8*)(h2src + bq * HP + quad * 8);
                const f16x8 b21 = *(const f16x8*)(h2src + bq * HP + quad * 8 + 32);
                f32x4 acc[4];
                #pragma unroll
                for (int g_ = 0; g_ < 4; ++g_) {
                    f32x4 a = __builtin_amdgcn_mfma_f32_16x16x32_f16(b10, wih[g_][0], biasf[g_], 0, 0, 0);
                    a = __builtin_amdgcn_mfma_f32_16x16x32_f16(b11, wih[g_][1], a, 0, 0, 0);
                    a = __builtin_amdgcn_mfma_f32_16x16x32_f16(b20, whh[g_][0], a, 0, 0, 0);
                    a = __builtin_amdgcn_mfma_f32_16x16x32_f16(b21, whh[g_][1], a, 0, 0, 0);
                    acc[g_] = a;
                }
                const float is = sig2_(acc[0][0]);
                const float fs = sig2_(acc[1][0]);
                const float gt = tanh2_(acc[2][0]);
                const float os = sig2_(acc[3][0]);
                creg = fs * creg + is * gt;
                const float h = os * tanh2_(creg * (2.0f * LOG2E));
                h2T[t & 1][quad * HP + 16 * w + n] = (_Float16)h;   // h2(t-1)
                if (t == TT) h2f[quad * 68 + 16 * w + n] = h;       // h2(TT-1) fp32
            }
        }
        __syncthreads();
    }

    // ---- epilogue: logits + softmax on fp32 h2 ----
    if (tid < 16) {
        const int b = tid & 3, o = tid >> 2;
        float acc = b_out[o];
        #pragma unroll
        for (int j = 0; j < HH; ++j)
            acc = fmaf(w_out[o * HH + j], h2f[b * 68 + j], acc);
        lg[b][o] = acc;
    }
    __syncthreads();
    if (tid < NB) {
        const int b = tid;
        const float l0 = lg[b][0], l1 = lg[b][1], l2 = lg[b][2], l3 = lg[b][3];
        const float m  = fmaxf(fmaxf(l0, l1), fmaxf(l2, l3));
        const float e0 = __expf(l0 - m), e1 = __expf(l1 - m);
        const float e2 = __expf(l2 - m), e3 = __expf(l3 - m);
        const float sum = 1.0f / (e0 + e1 + e2 + e3);
        out[(b0 + b) * 4 + 0] = e0 * sum;
        out[(b0 + b) * 4 + 1] = e1 * sum;
        out[(b0 + b) * 4 + 2] = e2 * sum;
        out[(b0 + b) * 4 + 3] = e3 * sum;
    }
}

extern "C" void kernel_launch(void* const* d_in, const int* in_sizes, int n_in,
                              void* d_out, int out_size, void* d_ws, size_t ws_size,
                              hipStream_t stream) {
    const float* x     = (const float*)d_in[0];
    const float* w_ih0 = (const float*)d_in[1];
    const float* w_hh0 = (const float*)d_in[2];
    const float* b_ih0 = (const float*)d_in[3];
    const float* b_hh0 = (const float*)d_in[4];
    const float* w_ih1 = (const float*)d_in[5];
    const float* w_hh1 = (const float*)d_in[6];
    const float* b_ih1 = (const float*)d_in[7];
    const float* b_hh1 = (const float*)d_in[8];
    const float* w_out = (const float*)d_in[9];
    const float* b_out = (const float*)d_in[10];
    float* out = (float*)d_out;

    hipLaunchKernelGGL(lstm_mfma, dim3(NBLK), dim3(512), 0, stream,
                       x, w_ih0, w_hh0, b_ih0, b_hh0,
                       w_ih1, w_hh1, b_ih1, b_hh1,
                       w_out, b_out, out);
}